// Round 1
// baseline (213.392 us; speedup 1.0000x reference)
//
#include <hip/hip_runtime.h>

#define NB 4
#define NP 32768
#define NK 16
#define ND 8
#define EPSV 1e-6f

// d_ws layout: [0..64) : 16 float accumulators (sum[8], sumsq[8]).
// x is NOT staged anymore: pass 2 recomputes it from the (L3-resident) inputs.
// This trades a 32 MB HBM write + 32 MB HBM read for ~16 MB of L3-hit re-reads.

// ---------------- Pass 1: stats only (read-only + 16 atomics/block) -------------------
// one thread per (b, n, kq) with kq = k/4  ->  4*32768*4 = 524288 threads, 2048 blocks
__global__ __launch_bounds__(256) void lse_stats(
    const float* __restrict__ coords,
    const int*   __restrict__ knn_idx,
    const float* __restrict__ knn_dist,
    const int*   __restrict__ mask,
    const float* __restrict__ conv_w,
    const float* __restrict__ conv_b,
    float*       __restrict__ accum)
{
    const int gid = blockIdx.x * 256 + threadIdx.x;
    const int b   = gid >> 17;                 // NP*4 = 2^17 threads per batch
    const int r   = gid & (NP * 4 - 1);
    const int n   = r >> 2;
    const int k0  = (r & 3) * 4;

    // Folded 1x1-conv weights: x_d = a.c + e.c_j + w9*dist + cb   (thread-uniform)
    float a0[ND], a1[ND], a2[ND], e0[ND], e1[ND], e2[ND], w9[ND], cb[ND];
#pragma unroll
    for (int d = 0; d < ND; ++d) {
        const float* w = conv_w + d * 10;
        a0[d] = w[0] + w[6]; a1[d] = w[1] + w[7]; a2[d] = w[2] + w[8];
        e0[d] = w[3] - w[6]; e1[d] = w[4] - w[7]; e2[d] = w[5] - w[8];
        w9[d] = w[9];        cb[d] = conv_b[d];
    }

    const float* cbase = coords + (size_t)b * NP * 3;
    const float  cx = cbase[n * 3 + 0];
    const float  cy = cbase[n * 3 + 1];
    const float  cz = cbase[n * 3 + 2];

    const size_t p  = ((size_t)(b * NP + n)) * NK + k0;
    const int4   id = *(const int4*)(knn_idx + p);     // 16B coalesced
    float4       dv = *(const float4*)(knn_dist + p);  // 16B coalesced
    if (mask[b * NP + n] == 0) {
        dv.x = dv.y = dv.z = dv.w = __builtin_inff();
    }

    const int   js[4] = {id.x < 0 ? 0 : id.x, id.y < 0 ? 0 : id.y,
                         id.z < 0 ? 0 : id.z, id.w < 0 ? 0 : id.w};
    const float ds[4] = {dv.x, dv.y, dv.z, dv.w};

    float sum[ND], sq[ND];
#pragma unroll
    for (int d = 0; d < ND; ++d) { sum[d] = 0.f; sq[d] = 0.f; }

#pragma unroll
    for (int t = 0; t < 4; ++t) {
        const float* nb = cbase + (size_t)js[t] * 3;   // L1/L2-resident gather (393 KB/batch)
        const float  nx = nb[0], ny = nb[1], nz = nb[2];
#pragma unroll
        for (int d = 0; d < ND; ++d) {
            float x = fmaf(a0[d], cx, fmaf(a1[d], cy, fmaf(a2[d], cz,
                      fmaf(e0[d], nx, fmaf(e1[d], ny, fmaf(e2[d], nz,
                      fmaf(w9[d], ds[t], cb[d])))))));
            sum[d] += x;
            sq[d]   = fmaf(x, x, sq[d]);
        }
    }

    // ---- stats reduction: wave shuffle -> LDS -> 16 atomics per block ----
#pragma unroll
    for (int d = 0; d < ND; ++d) {
        float s = sum[d], s2 = sq[d];
#pragma unroll
        for (int off = 32; off > 0; off >>= 1) {
            s  += __shfl_down(s,  off);
            s2 += __shfl_down(s2, off);
        }
        sum[d] = s; sq[d] = s2;
    }
    __shared__ float lds[4][16];
    const int wave = threadIdx.x >> 6, lane = threadIdx.x & 63;
    if (lane == 0) {
#pragma unroll
        for (int d = 0; d < ND; ++d) {
            lds[wave][d]     = sum[d];
            lds[wave][8 + d] = sq[d];
        }
    }
    __syncthreads();
    if (threadIdx.x < 16) {
        float v = lds[0][threadIdx.x] + lds[1][threadIdx.x]
                + lds[2][threadIdx.x] + lds[3][threadIdx.x];
        atomicAdd(&accum[threadIdx.x], v);
    }
}

// ---------------- Pass 2: recompute x + BN + relu + feature broadcast ------------------
// one thread per (b, n, kq) -> 524288 threads, 2048 blocks.
// Writes ALL 134 MB of output; inputs re-read from L3 (warm from pass 1).
__global__ __launch_bounds__(256) void lse_write(
    const float* __restrict__ coords,
    const float* __restrict__ features,
    const int*   __restrict__ knn_idx,
    const float* __restrict__ knn_dist,
    const int*   __restrict__ mask,
    const float* __restrict__ conv_w,
    const float* __restrict__ conv_b,
    const float* __restrict__ accum,
    const float* __restrict__ bn_gamma,
    const float* __restrict__ bn_beta,
    float*       __restrict__ out)
{
    const int gid = blockIdx.x * 256 + threadIdx.x;
    const int b   = gid >> 17;
    const int r   = gid & (NP * 4 - 1);
    const int n   = r >> 2;
    const int k0  = (r & 3) * 4;

    // Folded conv weights fused with BN scale/shift:
    //   y_d = relu(g_d * x_d + sh_d), x_d = a.c + e.c_j + w9*dist + cb
    // Fold g into the weights so the inner loop stays 7 fma per (t,d).
    const float invM = 1.0f / (float)(NB * NP * NK);
    float a0[ND], a1[ND], a2[ND], e0[ND], e1[ND], e2[ND], w9[ND], cb[ND];
#pragma unroll
    for (int d = 0; d < ND; ++d) {
        const float* w = conv_w + d * 10;
        const float mean = accum[d] * invM;
        const float var  = fmaf(-mean, mean, accum[8 + d] * invM);
        const float g    = bn_gamma[d] * rsqrtf(var + EPSV);
        const float sh   = fmaf(-mean, g, bn_beta[d]);
        a0[d] = (w[0] + w[6]) * g; a1[d] = (w[1] + w[7]) * g; a2[d] = (w[2] + w[8]) * g;
        e0[d] = (w[3] - w[6]) * g; e1[d] = (w[4] - w[7]) * g; e2[d] = (w[5] - w[8]) * g;
        w9[d] = w[9] * g;          cb[d] = fmaf(conv_b[d], g, sh);
    }

    const float* cbase = coords + (size_t)b * NP * 3;
    const float  cx = cbase[n * 3 + 0];
    const float  cy = cbase[n * 3 + 1];
    const float  cz = cbase[n * 3 + 2];

    const size_t p  = ((size_t)(b * NP + n)) * NK + k0;
    const int4   id = *(const int4*)(knn_idx + p);
    float4       dv = *(const float4*)(knn_dist + p);
    if (mask[b * NP + n] == 0) {
        dv.x = dv.y = dv.z = dv.w = __builtin_inff();
    }

    const int   js[4] = {id.x < 0 ? 0 : id.x, id.y < 0 ? 0 : id.y,
                         id.z < 0 ? 0 : id.z, id.w < 0 ? 0 : id.w};
    const float ds[4] = {dv.x, dv.y, dv.z, dv.w};

    float xv[4][ND];
#pragma unroll
    for (int t = 0; t < 4; ++t) {
        const float* nb = cbase + (size_t)js[t] * 3;
        const float  nx = nb[0], ny = nb[1], nz = nb[2];
#pragma unroll
        for (int d = 0; d < ND; ++d) {
            // BN+conv fused: this IS g*x+sh already
            xv[t][d] = fmaf(a0[d], cx, fmaf(a1[d], cy, fmaf(a2[d], cz,
                       fmaf(e0[d], nx, fmaf(e1[d], ny, fmaf(e2[d], nz,
                       fmaf(w9[d], ds[t], cb[d])))))));
        }
    }

    // x-part planes (channels 0..ND-1): relu + store, 64 lanes -> 1 KB contiguous/plane
#pragma unroll
    for (int d = 0; d < ND; ++d) {
        float4 v;
        v.x = fmaxf(xv[0][d], 0.f);
        v.y = fmaxf(xv[1][d], 0.f);
        v.z = fmaxf(xv[2][d], 0.f);
        v.w = fmaxf(xv[3][d], 0.f);
        *(float4*)(out + ((((size_t)(b * 2 * ND + d)) * NP + n) << 4) + k0) = v;
    }

    // feature broadcast planes (channels ND..2ND-1)
    const float* fb = features + (size_t)b * ND * NP;
#pragma unroll
    for (int d = 0; d < ND; ++d) {
        const float v = fb[d * NP + n];
        *(float4*)(out + ((((size_t)(b * 2 * ND + ND + d)) * NP + n) << 4) + k0) =
            make_float4(v, v, v, v);
    }
}

extern "C" void kernel_launch(void* const* d_in, const int* in_sizes, int n_in,
                              void* d_out, int out_size, void* d_ws, size_t ws_size,
                              hipStream_t stream) {
    const float* coords   = (const float*)d_in[0];
    const float* features = (const float*)d_in[1];
    const int*   knn_idx  = (const int*)  d_in[2];
    const float* knn_dist = (const float*)d_in[3];
    const int*   mask     = (const int*)  d_in[4];
    const float* conv_w   = (const float*)d_in[5];
    const float* conv_b   = (const float*)d_in[6];
    const float* bn_gamma = (const float*)d_in[7];
    const float* bn_beta  = (const float*)d_in[8];
    float* out   = (float*)d_out;
    float* accum = (float*)d_ws;   // 16 floats

    hipMemsetAsync(d_ws, 0, 64, stream);

    // pass 1: stats only (reads ~18 MB, writes 16 floats)
    lse_stats<<<(NB * NP * 4) / 256, 256, 0, stream>>>(
        coords, knn_idx, knn_dist, mask, conv_w, conv_b, accum);

    // pass 2: recompute + BN + relu + feature broadcast (writes all 134 MB)
    lse_write<<<(NB * NP * 4) / 256, 256, 0, stream>>>(
        coords, features, knn_idx, knn_dist, mask, conv_w, conv_b,
        accum, bn_gamma, bn_beta, out);
}